// Round 11
// baseline (177.018 us; speedup 1.0000x reference)
//
#include <hip/hip_runtime.h>
#include <hip/hip_bf16.h>

// B=2, T=2048, D=1024, H=16, Hd=64. Inputs/outputs f32; compute bf16 MFMA.

typedef __bf16 bf16;
typedef bf16 bf16x8 __attribute__((ext_vector_type(8)));
typedef bf16 bf16x4 __attribute__((ext_vector_type(4)));
typedef float f32x4 __attribute__((ext_vector_type(4)));

#define MFMA16(a, b, c) __builtin_amdgcn_mfma_f32_16x16x32_bf16((a), (b), (c), 0, 0, 0)

static constexpr int D_MODEL = 1024;
static constexpr int NH = 16;
static constexpr int HD = 64;
static constexpr int SEQ = 2048;
static constexpr int NB = 2;
static constexpr float QSCALE = 0.125f * 1.44269504088896340736f; // 1/sqrt(64)*log2(e)

__device__ __forceinline__ bf16x8 cvt8(const float* p) {
    float4 u0 = *(const float4*)p;
    float4 u1 = *(const float4*)(p + 4);
    bf16x8 v = { (bf16)u0.x, (bf16)u0.y, (bf16)u0.z, (bf16)u0.w,
                 (bf16)u1.x, (bf16)u1.y, (bf16)u1.z, (bf16)u1.w };
    return v;
}

// async global->LDS, 16 B per lane (LDS dest = wave-uniform base + lane*16).
__device__ __forceinline__ void async16(const bf16* g, bf16* l) {
    __builtin_amdgcn_global_load_lds(
        (const __attribute__((address_space(1))) void*)g,
        (__attribute__((address_space(3))) void*)l, 16, 0, 0);
}

// ---------------------------------------------------------------------------
// Kernel 0: merged f32 -> bf16 cast for all three tensors (R16, one launch).
// ---------------------------------------------------------------------------
static constexpr int X8 = 524288;
static constexpr int W8 = 917504;   // X8 + 393216
static constexpr int T8 = 1048576;  // W8 + 131072

__global__ __launch_bounds__(256)
void k_cast_all(const float* __restrict__ x, const float* __restrict__ qkv_w,
                const float* __restrict__ out_w,
                bf16* __restrict__ xb, bf16* __restrict__ wqb,
                bf16* __restrict__ wob)
{
    int i = blockIdx.x * 256 + threadIdx.x;
    if (i < X8) {
        *(bf16x8*)&xb[(size_t)i * 8] = cvt8(&x[(size_t)i * 8]);
    } else if (i < W8) {
        int j = i - X8;
        *(bf16x8*)&wqb[(size_t)j * 8] = cvt8(&qkv_w[(size_t)j * 8]);
    } else if (i < T8) {
        int j = i - W8;
        *(bf16x8*)&wob[(size_t)j * 8] = cvt8(&out_w[(size_t)j * 8]);
    }
}

// ---------------------------------------------------------------------------
// Kernel 1: QKV projection — R20: port of the R19-verified oproj template:
// 128x128 tile, BK 32 -> 64 (16 barrier pairs instead of 32), 16B-chunk XOR
// swizzle (write source chunk (t&7)^(row&7), read chunk ((kk*4+lk)^(lr&7));
// read rows wm*64+i*16+lr ≡ lr mod 8 so the XOR cancels — same algebra
// verified numerically in R19 oproj and R8 qkv). Kills the 3.1M
// SQ_LDS_BANK_CONFLICT the flat [row][32] layout logged (R5 counters) and
// halves barrier count. A and W each staged as 4 pieces x 32 rows x 64 k
// (2048 elems/piece, 256 threads x 16B). LDS 32 KB, 3 blocks/CU (grid 768).
// Q -> [B,H,T,64] (pre-scaled), K -> [B,H,T,64], V -> transposed [B,H,64,T].
// ---------------------------------------------------------------------------
__global__ __launch_bounds__(256)
void k_qkv(const bf16* __restrict__ x, const bf16* __restrict__ w,
           const float* __restrict__ bias,
           bf16* __restrict__ Qb, bf16* __restrict__ Kb, bf16* __restrict__ VbT)
{
    __shared__ bf16 As[128 * 64];   // 16 KB, swizzled 16B chunks
    __shared__ bf16 Ws[128 * 64];   // 16 KB, swizzled

    const int tid  = threadIdx.x;
    const int wv   = tid >> 6;
    const int lane = tid & 63;
    const int lr   = lane & 15;
    const int lk   = lane >> 4;
    const int wm   = wv >> 1, wn = wv & 1;
    const int m0   = blockIdx.x * 128;
    const int n0   = blockIdx.y * 128;

    const int srow   = tid >> 3;                 // 0..31 (row within 32-row piece)
    const int schunk = (tid & 7) ^ (srow & 7);   // swizzled source chunk
    const int sldse  = tid * 8;                  // linear LDS elem within piece
    const int swz    = lr & 7;                   // read-side swizzle key

    f32x4 acc[4][4] = {};

    for (int kt = 0; kt < 1024; kt += 64) {
        __syncthreads();
        #pragma unroll
        for (int l = 0; l < 4; l++)     // A: 4 pieces x 32 rows x 64 k (2048 elems each)
            async16(&x[(size_t)(m0 + l * 32 + srow) * 1024 + kt + schunk * 8],
                    &As[l * 2048 + sldse]);
        #pragma unroll
        for (int l = 0; l < 4; l++)     // W: 4 pieces x 32 rows x 64 k
            async16(&w[(size_t)(n0 + l * 32 + srow) * 1024 + kt + schunk * 8],
                    &Ws[l * 2048 + sldse]);
        __syncthreads();

        #pragma unroll
        for (int kk = 0; kk < 2; kk++) {
            bf16x8 a[4], b[4];
            #pragma unroll
            for (int i = 0; i < 4; i++) {
                a[i] = *(const bf16x8*)
                    &As[(wm * 64 + i * 16 + lr) * 64 + (((kk * 4 + lk) ^ swz) << 3)];
                b[i] = *(const bf16x8*)
                    &Ws[(wn * 64 + i * 16 + lr) * 64 + (((kk * 4 + lk) ^ swz) << 3)];
            }
            #pragma unroll
            for (int i = 0; i < 4; i++)
                #pragma unroll
                for (int j = 0; j < 4; j++)
                    acc[i][j] = MFMA16(a[i], b[j], acc[i][j]);
        }
    }

    // C/D layout: col = lane&15, row = (lane>>4)*4 + reg
    #pragma unroll
    for (int i = 0; i < 4; i++) {
        #pragma unroll
        for (int j = 0; j < 4; j++) {
            const int gm0 = m0 + wm * 64 + i * 16 + lk * 4;
            const int gn  = n0 + wn * 64 + j * 16 + lr;
            const int sel = gn >> 10;
            const int rem = gn & 1023;
            const int h   = rem >> 6;
            const int hd  = rem & 63;
            const int bb  = gm0 >> 11;
            const int t0  = gm0 & 2047;
            if (sel == 2) {
                bf16x4 p;
                #pragma unroll
                for (int r = 0; r < 4; r++) p[r] = (bf16)(acc[i][j][r] + bias[gn]);
                *(bf16x4*)&VbT[((size_t)(bb * NH + h) * HD + hd) * SEQ + t0] = p;
            } else {
                #pragma unroll
                for (int r = 0; r < 4; r++) {
                    float v = acc[i][j][r] + bias[gn];
                    size_t idx = ((size_t)(bb * NH + h) * SEQ + t0 + r) * HD + hd;
                    if (sel == 0) Qb[idx] = (bf16)(v * QSCALE);
                    else          Kb[idx] = (bf16)v;
                }
            }
        }
    }
}

// ---------------------------------------------------------------------------
// Kernel 2: causal flash attention — exact R1 version (best measured).
// QBLK=64, 4 waves x 16 q; double-buffered K/V via global_load_lds one tile
// ahead; counted vmcnt(4) + raw s_barrier; 16B-chunk XOR swizzle with
// pre-swizzled global source; no-max softmax with HW exp; S^T = K·Q^T.
// R2 (fat waves) and R15 (8 thin waves) both regressed — do not re-fatten.
// ---------------------------------------------------------------------------
__global__ __launch_bounds__(256)
void k_attn(const bf16* __restrict__ Qb, const bf16* __restrict__ Kb,
            const bf16* __restrict__ VbT, bf16* __restrict__ AO)
{
    __shared__ bf16 Ks[2][64 * 64];
    __shared__ bf16 Vt[2][64 * 64];
    __shared__ bf16 Ps[64 * 64];

    const int tid  = threadIdx.x;
    const int wv   = tid >> 6;
    const int lane = tid & 63;
    const int lr   = lane & 15;
    const int lk   = lane >> 4;
    const int bh   = blockIdx.y;
    const int qt   = ((bh >> 3) & 1) ? (31 - (int)blockIdx.x) : (int)blockIdx.x;

    const bf16* Qp  = Qb  + (size_t)bh * SEQ * HD;
    const bf16* Kp  = Kb  + (size_t)bh * SEQ * HD;
    const bf16* Vtp = VbT + (size_t)bh * HD * SEQ;

    const int qg = qt * 64 + wv * 16 + lr;

    bf16x8 qf[2];
    qf[0] = *(const bf16x8*)&Qp[(size_t)qg * HD +      lk * 8];
    qf[1] = *(const bf16x8*)&Qp[(size_t)qg * HD + 32 + lk * 8];

    f32x4 ot[4] = {};
    float lsum = 0.f;

    const int srow   = tid >> 3;
    const int sgcol  = ((tid & 7) ^ (srow & 7)) * 8;
    const int sldse  = tid * 8;
    const int swz    = lr & 7;

    auto stage = [&](int buf, int k0) {
        async16(&Kp [(size_t)(k0 + srow     ) * HD  + sgcol], &Ks[buf][       sldse]);
        async16(&Kp [(size_t)(k0 + 32 + srow) * HD  + sgcol], &Ks[buf][2048 + sldse]);
        async16(&Vtp[(size_t)(srow          ) * SEQ + k0 + sgcol], &Vt[buf][       sldse]);
        async16(&Vtp[(size_t)(32 + srow     ) * SEQ + k0 + sgcol], &Vt[buf][2048 + sldse]);
    };

    stage(0, 0);

    for (int kt = 0; kt <= qt; kt++) {
        const int p = kt & 1;
        if (kt < qt) {
            stage(p ^ 1, (kt + 1) * 64);
            asm volatile("s_waitcnt vmcnt(4)" ::: "memory");
        } else {
            asm volatile("s_waitcnt vmcnt(0)" ::: "memory");
        }
        __builtin_amdgcn_s_barrier();

        f32x4 s[4] = {};
        #pragma unroll
        for (int j = 0; j < 4; j++) {
            #pragma unroll
            for (int c = 0; c < 2; c++) {
                bf16x8 ka = *(const bf16x8*)
                    &Ks[p][(j * 16 + lr) * 64 + (((4 * c + lk) ^ swz) << 3)];
                s[j] = MFMA16(ka, qf[c], s[j]);
            }
        }

        const int k0 = kt * 64;
        const bool diag = (kt == qt);
        #pragma unroll
        for (int j = 0; j < 4; j++) {
            const int keyb = k0 + j * 16 + lk * 4;
            f32x4 pv;
            #pragma unroll
            for (int r = 0; r < 4; r++) {
                float e = __builtin_amdgcn_exp2f(s[j][r]);
                if (diag) e = (keyb + r > qg) ? 0.f : e;
                pv[r] = e;
            }
            s[j] = pv;
            lsum += (pv[0] + pv[1]) + (pv[2] + pv[3]);
        }

        #pragma unroll
        for (int j = 0; j < 4; j++) {
            bf16x4 p4 = { (bf16)s[j][0], (bf16)s[j][1], (bf16)s[j][2], (bf16)s[j][3] };
            *(bf16x4*)&Ps[(wv * 16 + lr) * 64 +
                          (((2 * j + (lk >> 1)) ^ swz) << 3) + ((lk & 1) << 2)] = p4;
        }

        #pragma unroll
        for (int c = 0; c < 2; c++) {
            bf16x8 pb = *(const bf16x8*)
                &Ps[(wv * 16 + lr) * 64 + (((4 * c + lk) ^ swz) << 3)];
            #pragma unroll
            for (int jh = 0; jh < 4; jh++) {
                bf16x8 va = *(const bf16x8*)
                    &Vt[p][(jh * 16 + lr) * 64 + (((4 * c + lk) ^ swz) << 3)];
                ot[jh] = MFMA16(va, pb, ot[jh]);
            }
        }

        asm volatile("" ::: "memory");
        __builtin_amdgcn_s_barrier();
    }

    lsum += __shfl_xor(lsum, 16);
    lsum += __shfl_xor(lsum, 32);

    const float inv = 1.0f / lsum;
    const int b_ = bh >> 4, h_ = bh & 15;
    const size_t base = ((size_t)(b_ * SEQ + qg)) * D_MODEL + h_ * HD;
    #pragma unroll
    for (int jh = 0; jh < 4; jh++) {
        bf16x4 o4 = { (bf16)(ot[jh][0] * inv), (bf16)(ot[jh][1] * inv),
                      (bf16)(ot[jh][2] * inv), (bf16)(ot[jh][3] * inv) };
        *(bf16x4*)&AO[base + jh * 16 + lk * 4] = o4;
    }
}

// ---------------------------------------------------------------------------
// Kernel 3: output projection — R19 (measured good: total 171.5 -> 168.9):
// 128x64 tile, BK=64, 16 barriers, swizzled 16B chunks (write source chunk
// (t&7)^(row&7), read ((kk*4+lk)^(lr&7))), piece stride 2048. 24 KB LDS.
// ---------------------------------------------------------------------------
__global__ __launch_bounds__(256)
void k_oproj(const bf16* __restrict__ a_, const bf16* __restrict__ w,
             const float* __restrict__ bias, float* __restrict__ out)
{
    __shared__ bf16 As[128 * 64];   // 16 KB, swizzled 16B chunks
    __shared__ bf16 Ws[64 * 64];    //  8 KB, swizzled

    const int tid  = threadIdx.x;
    const int wv   = tid >> 6;
    const int lane = tid & 63;
    const int lr   = lane & 15;
    const int lk   = lane >> 4;
    const int wm   = wv >> 1, wn = wv & 1;
    const int m0   = blockIdx.x * 128;
    const int n0   = blockIdx.y * 64;

    const int srow   = tid >> 3;                 // 0..31 (row within 32-row piece)
    const int schunk = (tid & 7) ^ (srow & 7);   // swizzled source chunk
    const int sldse  = tid * 8;                  // linear LDS elem within piece
    const int swz    = lr & 7;                   // read-side swizzle key

    f32x4 acc[4][2] = {};

    for (int kt = 0; kt < 1024; kt += 64) {
        __syncthreads();
        #pragma unroll
        for (int l = 0; l < 4; l++)     // A: 4 pieces x 32 rows x 64 k (2048 elems each)
            async16(&a_[(size_t)(m0 + l * 32 + srow) * 1024 + kt + schunk * 8],
                    &As[l * 2048 + sldse]);
        #pragma unroll
        for (int l = 0; l < 2; l++)     // W: 2 pieces x 32 rows x 64 k
            async16(&w [(size_t)(n0 + l * 32 + srow) * 1024 + kt + schunk * 8],
                    &Ws[l * 2048 + sldse]);
        __syncthreads();

        #pragma unroll
        for (int kk = 0; kk < 2; kk++) {
            bf16x8 a[4], b[2];
            #pragma unroll
            for (int i = 0; i < 4; i++)
                a[i] = *(const bf16x8*)
                    &As[(wm * 64 + i * 16 + lr) * 64 + (((kk * 4 + lk) ^ swz) << 3)];
            #pragma unroll
            for (int j = 0; j < 2; j++)
                b[j] = *(const bf16x8*)
                    &Ws[(wn * 32 + j * 16 + lr) * 64 + (((kk * 4 + lk) ^ swz) << 3)];
            #pragma unroll
            for (int i = 0; i < 4; i++)
                #pragma unroll
                for (int j = 0; j < 2; j++)
                    acc[i][j] = MFMA16(a[i], b[j], acc[i][j]);
        }
    }

    #pragma unroll
    for (int i = 0; i < 4; i++) {
        #pragma unroll
        for (int j = 0; j < 2; j++) {
            #pragma unroll
            for (int r = 0; r < 4; r++) {
                int gm = m0 + wm * 64 + i * 16 + lk * 4 + r;
                int gn = n0 + wn * 32 + j * 16 + lr;
                out[(size_t)gm * 1024 + gn] = acc[i][j][r] + bias[gn];
            }
        }
    }
}

// ---------------------------------------------------------------------------
extern "C" void kernel_launch(void* const* d_in, const int* in_sizes, int n_in,
                              void* d_out, int out_size, void* d_ws, size_t ws_size,
                              hipStream_t stream)
{
    const float* x     = (const float*)d_in[0];
    const float* qkv_w = (const float*)d_in[1];
    const float* qkv_b = (const float*)d_in[2];
    const float* out_w = (const float*)d_in[3];
    const float* out_b = (const float*)d_in[4];
    float* out = (float*)d_out;

    const size_t SZ = (size_t)NB * NH * SEQ * HD;      // 4,194,304
    bf16* Qb  = (bf16*)d_ws;
    bf16* Kb  = Qb + SZ;
    bf16* VbT = Kb + SZ;
    bf16* AO  = VbT + SZ;
    bf16* xb  = AO + SZ;
    bf16* wqb = xb + SZ;
    bf16* wob = wqb + (size_t)3 * D_MODEL * D_MODEL;

    hipLaunchKernelGGL(k_cast_all, dim3(4096), dim3(256), 0, stream,
                       x, qkv_w, out_w, xb, wqb, wob);

    hipLaunchKernelGGL(k_qkv, dim3(32, 24), dim3(256), 0, stream,
                       xb, wqb, qkv_b, Qb, Kb, VbT);
    hipLaunchKernelGGL(k_attn, dim3(32, 32), dim3(256), 0, stream,
                       Qb, Kb, VbT, AO);
    hipLaunchKernelGGL(k_oproj, dim3(32, 16), dim3(256), 0, stream,
                       AO, wob, out_b, out);
}

// Round 12
// 172.115 us; speedup vs baseline: 1.0285x; 1.0285x over previous
//
#include <hip/hip_runtime.h>
#include <hip/hip_bf16.h>

// B=2, T=2048, D=1024, H=16, Hd=64. Inputs/outputs f32; compute bf16 MFMA.

typedef __bf16 bf16;
typedef bf16 bf16x8 __attribute__((ext_vector_type(8)));
typedef bf16 bf16x4 __attribute__((ext_vector_type(4)));
typedef float f32x4 __attribute__((ext_vector_type(4)));

#define MFMA16(a, b, c) __builtin_amdgcn_mfma_f32_16x16x32_bf16((a), (b), (c), 0, 0, 0)

static constexpr int D_MODEL = 1024;
static constexpr int NH = 16;
static constexpr int HD = 64;
static constexpr int SEQ = 2048;
static constexpr int NB = 2;
static constexpr float QSCALE = 0.125f * 1.44269504088896340736f; // 1/sqrt(64)*log2(e)

__device__ __forceinline__ bf16x8 cvt8(const float* p) {
    float4 u0 = *(const float4*)p;
    float4 u1 = *(const float4*)(p + 4);
    bf16x8 v = { (bf16)u0.x, (bf16)u0.y, (bf16)u0.z, (bf16)u0.w,
                 (bf16)u1.x, (bf16)u1.y, (bf16)u1.z, (bf16)u1.w };
    return v;
}

// async global->LDS, 16 B per lane (LDS dest = wave-uniform base + lane*16).
__device__ __forceinline__ void async16(const bf16* g, bf16* l) {
    __builtin_amdgcn_global_load_lds(
        (const __attribute__((address_space(1))) void*)g,
        (__attribute__((address_space(3))) void*)l, 16, 0, 0);
}

// ---------------------------------------------------------------------------
// Kernel 0: merged f32 -> bf16 cast for all three tensors (R16, one launch).
// ---------------------------------------------------------------------------
static constexpr int X8 = 524288;
static constexpr int W8 = 917504;   // X8 + 393216
static constexpr int T8 = 1048576;  // W8 + 131072

__global__ __launch_bounds__(256)
void k_cast_all(const float* __restrict__ x, const float* __restrict__ qkv_w,
                const float* __restrict__ out_w,
                bf16* __restrict__ xb, bf16* __restrict__ wqb,
                bf16* __restrict__ wob)
{
    int i = blockIdx.x * 256 + threadIdx.x;
    if (i < X8) {
        *(bf16x8*)&xb[(size_t)i * 8] = cvt8(&x[(size_t)i * 8]);
    } else if (i < W8) {
        int j = i - X8;
        *(bf16x8*)&wqb[(size_t)j * 8] = cvt8(&qkv_w[(size_t)j * 8]);
    } else if (i < T8) {
        int j = i - W8;
        *(bf16x8*)&wob[(size_t)j * 8] = cvt8(&out_w[(size_t)j * 8]);
    }
}

// ---------------------------------------------------------------------------
// Kernel 1: QKV projection — R21: R1 structure (128x128, BK=32, syncthreads,
// single-buffer — R11 proved BK=64 regresses here: VGPR 88, occupancy 14%,
// long 8-load drains) + 4-chunk XOR swizzle to cut the flat-[row][32]
// layout's 8-way ds_read_b128 bank conflict to the 4-way floor (a 64 B row
// has only 4 16B chunks). Staging keeps the LINEAR LDS dest (tid*16 B) and
// swizzles the GLOBAL column: chunk (t&3)^(srow&3); read chunk lk^(lr&3).
// Rows ≡ lr mod 4 (64,16 ≡ 0 mod 4) so the XOR cancels -> same data as R1.
// Q -> [B,H,T,64] (pre-scaled), K -> [B,H,T,64], V -> transposed [B,H,64,T].
// ---------------------------------------------------------------------------
__global__ __launch_bounds__(256)
void k_qkv(const bf16* __restrict__ x, const bf16* __restrict__ w,
           const float* __restrict__ bias,
           bf16* __restrict__ Qb, bf16* __restrict__ Kb, bf16* __restrict__ VbT)
{
    __shared__ bf16 As[128 * 32];   // 8 KB, flat, 16B-chunk swizzled (mod 4)
    __shared__ bf16 Ws[128 * 32];

    const int tid  = threadIdx.x;
    const int wv   = tid >> 6;
    const int lane = tid & 63;
    const int lr   = lane & 15;
    const int lk   = lane >> 4;
    const int wm   = wv >> 1, wn = wv & 1;
    const int m0   = blockIdx.x * 128;
    const int n0   = blockIdx.y * 128;

    const int sRow  = tid >> 2;                        // 0..63
    const int sColS = ((tid & 3) ^ (sRow & 3)) * 8;    // swizzled GLOBAL col
    const int sOff  = tid * 8;                         // linear LDS dest (16B/lane)
    const int swz4  = lr & 3;                          // read-side swizzle key

    f32x4 acc[4][4] = {};

    for (int kt = 0; kt < 1024; kt += 32) {
        __syncthreads();
        async16(&x[(size_t)(m0 + sRow     ) * 1024 + kt + sColS], &As[sOff]);
        async16(&x[(size_t)(m0 + 64 + sRow) * 1024 + kt + sColS], &As[64 * 32 + sOff]);
        async16(&w[(size_t)(n0 + sRow     ) * 1024 + kt + sColS], &Ws[sOff]);
        async16(&w[(size_t)(n0 + 64 + sRow) * 1024 + kt + sColS], &Ws[64 * 32 + sOff]);
        __syncthreads();

        bf16x8 a[4], b[4];
        #pragma unroll
        for (int i = 0; i < 4; i++) {
            a[i] = *(const bf16x8*)&As[(wm * 64 + i * 16 + lr) * 32 + ((lk ^ swz4) * 8)];
            b[i] = *(const bf16x8*)&Ws[(wn * 64 + i * 16 + lr) * 32 + ((lk ^ swz4) * 8)];
        }
        #pragma unroll
        for (int i = 0; i < 4; i++)
            #pragma unroll
            for (int j = 0; j < 4; j++)
                acc[i][j] = MFMA16(a[i], b[j], acc[i][j]);
    }

    // C/D layout: col = lane&15, row = (lane>>4)*4 + reg
    #pragma unroll
    for (int i = 0; i < 4; i++) {
        #pragma unroll
        for (int j = 0; j < 4; j++) {
            const int gm0 = m0 + wm * 64 + i * 16 + lk * 4;
            const int gn  = n0 + wn * 64 + j * 16 + lr;
            const int sel = gn >> 10;
            const int rem = gn & 1023;
            const int h   = rem >> 6;
            const int hd  = rem & 63;
            const int bb  = gm0 >> 11;
            const int t0  = gm0 & 2047;
            if (sel == 2) {
                bf16x4 p;
                #pragma unroll
                for (int r = 0; r < 4; r++) p[r] = (bf16)(acc[i][j][r] + bias[gn]);
                *(bf16x4*)&VbT[((size_t)(bb * NH + h) * HD + hd) * SEQ + t0] = p;
            } else {
                #pragma unroll
                for (int r = 0; r < 4; r++) {
                    float v = acc[i][j][r] + bias[gn];
                    size_t idx = ((size_t)(bb * NH + h) * SEQ + t0 + r) * HD + hd;
                    if (sel == 0) Qb[idx] = (bf16)(v * QSCALE);
                    else          Kb[idx] = (bf16)v;
                }
            }
        }
    }
}

// ---------------------------------------------------------------------------
// Kernel 2: causal flash attention — exact R1 version (best measured).
// QBLK=64, 4 waves x 16 q; double-buffered K/V via global_load_lds one tile
// ahead; counted vmcnt(4) + raw s_barrier; 16B-chunk XOR swizzle with
// pre-swizzled global source; no-max softmax with HW exp; S^T = K·Q^T.
// R2 (fat waves) and R15 (8 thin waves) both regressed — do not re-fatten.
// ---------------------------------------------------------------------------
__global__ __launch_bounds__(256)
void k_attn(const bf16* __restrict__ Qb, const bf16* __restrict__ Kb,
            const bf16* __restrict__ VbT, bf16* __restrict__ AO)
{
    __shared__ bf16 Ks[2][64 * 64];
    __shared__ bf16 Vt[2][64 * 64];
    __shared__ bf16 Ps[64 * 64];

    const int tid  = threadIdx.x;
    const int wv   = tid >> 6;
    const int lane = tid & 63;
    const int lr   = lane & 15;
    const int lk   = lane >> 4;
    const int bh   = blockIdx.y;
    const int qt   = ((bh >> 3) & 1) ? (31 - (int)blockIdx.x) : (int)blockIdx.x;

    const bf16* Qp  = Qb  + (size_t)bh * SEQ * HD;
    const bf16* Kp  = Kb  + (size_t)bh * SEQ * HD;
    const bf16* Vtp = VbT + (size_t)bh * HD * SEQ;

    const int qg = qt * 64 + wv * 16 + lr;

    bf16x8 qf[2];
    qf[0] = *(const bf16x8*)&Qp[(size_t)qg * HD +      lk * 8];
    qf[1] = *(const bf16x8*)&Qp[(size_t)qg * HD + 32 + lk * 8];

    f32x4 ot[4] = {};
    float lsum = 0.f;

    const int srow   = tid >> 3;
    const int sgcol  = ((tid & 7) ^ (srow & 7)) * 8;
    const int sldse  = tid * 8;
    const int swz    = lr & 7;

    auto stage = [&](int buf, int k0) {
        async16(&Kp [(size_t)(k0 + srow     ) * HD  + sgcol], &Ks[buf][       sldse]);
        async16(&Kp [(size_t)(k0 + 32 + srow) * HD  + sgcol], &Ks[buf][2048 + sldse]);
        async16(&Vtp[(size_t)(srow          ) * SEQ + k0 + sgcol], &Vt[buf][       sldse]);
        async16(&Vtp[(size_t)(32 + srow     ) * SEQ + k0 + sgcol], &Vt[buf][2048 + sldse]);
    };

    stage(0, 0);

    for (int kt = 0; kt <= qt; kt++) {
        const int p = kt & 1;
        if (kt < qt) {
            stage(p ^ 1, (kt + 1) * 64);
            asm volatile("s_waitcnt vmcnt(4)" ::: "memory");
        } else {
            asm volatile("s_waitcnt vmcnt(0)" ::: "memory");
        }
        __builtin_amdgcn_s_barrier();

        f32x4 s[4] = {};
        #pragma unroll
        for (int j = 0; j < 4; j++) {
            #pragma unroll
            for (int c = 0; c < 2; c++) {
                bf16x8 ka = *(const bf16x8*)
                    &Ks[p][(j * 16 + lr) * 64 + (((4 * c + lk) ^ swz) << 3)];
                s[j] = MFMA16(ka, qf[c], s[j]);
            }
        }

        const int k0 = kt * 64;
        const bool diag = (kt == qt);
        #pragma unroll
        for (int j = 0; j < 4; j++) {
            const int keyb = k0 + j * 16 + lk * 4;
            f32x4 pv;
            #pragma unroll
            for (int r = 0; r < 4; r++) {
                float e = __builtin_amdgcn_exp2f(s[j][r]);
                if (diag) e = (keyb + r > qg) ? 0.f : e;
                pv[r] = e;
            }
            s[j] = pv;
            lsum += (pv[0] + pv[1]) + (pv[2] + pv[3]);
        }

        #pragma unroll
        for (int j = 0; j < 4; j++) {
            bf16x4 p4 = { (bf16)s[j][0], (bf16)s[j][1], (bf16)s[j][2], (bf16)s[j][3] };
            *(bf16x4*)&Ps[(wv * 16 + lr) * 64 +
                          (((2 * j + (lk >> 1)) ^ swz) << 3) + ((lk & 1) << 2)] = p4;
        }

        #pragma unroll
        for (int c = 0; c < 2; c++) {
            bf16x8 pb = *(const bf16x8*)
                &Ps[(wv * 16 + lr) * 64 + (((4 * c + lk) ^ swz) << 3)];
            #pragma unroll
            for (int jh = 0; jh < 4; jh++) {
                bf16x8 va = *(const bf16x8*)
                    &Vt[p][(jh * 16 + lr) * 64 + (((4 * c + lk) ^ swz) << 3)];
                ot[jh] = MFMA16(va, pb, ot[jh]);
            }
        }

        asm volatile("" ::: "memory");
        __builtin_amdgcn_s_barrier();
    }

    lsum += __shfl_xor(lsum, 16);
    lsum += __shfl_xor(lsum, 32);

    const float inv = 1.0f / lsum;
    const int b_ = bh >> 4, h_ = bh & 15;
    const size_t base = ((size_t)(b_ * SEQ + qg)) * D_MODEL + h_ * HD;
    #pragma unroll
    for (int jh = 0; jh < 4; jh++) {
        bf16x4 o4 = { (bf16)(ot[jh][0] * inv), (bf16)(ot[jh][1] * inv),
                      (bf16)(ot[jh][2] * inv), (bf16)(ot[jh][3] * inv) };
        *(bf16x4*)&AO[base + jh * 16 + lk * 4] = o4;
    }
}

// ---------------------------------------------------------------------------
// Kernel 3: output projection — R19 (measured good: total 171.5 -> 168.9):
// 128x64 tile, BK=64, 16 barriers, swizzled 16B chunks (write source chunk
// (t&7)^(row&7), read ((kk*4+lk)^(lr&7))), piece stride 2048. 24 KB LDS.
// ---------------------------------------------------------------------------
__global__ __launch_bounds__(256)
void k_oproj(const bf16* __restrict__ a_, const bf16* __restrict__ w,
             const float* __restrict__ bias, float* __restrict__ out)
{
    __shared__ bf16 As[128 * 64];   // 16 KB, swizzled 16B chunks
    __shared__ bf16 Ws[64 * 64];    //  8 KB, swizzled

    const int tid  = threadIdx.x;
    const int wv   = tid >> 6;
    const int lane = tid & 63;
    const int lr   = lane & 15;
    const int lk   = lane >> 4;
    const int wm   = wv >> 1, wn = wv & 1;
    const int m0   = blockIdx.x * 128;
    const int n0   = blockIdx.y * 64;

    const int srow   = tid >> 3;                 // 0..31 (row within 32-row piece)
    const int schunk = (tid & 7) ^ (srow & 7);   // swizzled source chunk
    const int sldse  = tid * 8;                  // linear LDS elem within piece
    const int swz    = lr & 7;                   // read-side swizzle key

    f32x4 acc[4][2] = {};

    for (int kt = 0; kt < 1024; kt += 64) {
        __syncthreads();
        #pragma unroll
        for (int l = 0; l < 4; l++)     // A: 4 pieces x 32 rows x 64 k (2048 elems each)
            async16(&a_[(size_t)(m0 + l * 32 + srow) * 1024 + kt + schunk * 8],
                    &As[l * 2048 + sldse]);
        #pragma unroll
        for (int l = 0; l < 2; l++)     // W: 2 pieces x 32 rows x 64 k
            async16(&w [(size_t)(n0 + l * 32 + srow) * 1024 + kt + schunk * 8],
                    &Ws[l * 2048 + sldse]);
        __syncthreads();

        #pragma unroll
        for (int kk = 0; kk < 2; kk++) {
            bf16x8 a[4], b[2];
            #pragma unroll
            for (int i = 0; i < 4; i++)
                a[i] = *(const bf16x8*)
                    &As[(wm * 64 + i * 16 + lr) * 64 + (((kk * 4 + lk) ^ swz) << 3)];
            #pragma unroll
            for (int j = 0; j < 2; j++)
                b[j] = *(const bf16x8*)
                    &Ws[(wn * 32 + j * 16 + lr) * 64 + (((kk * 4 + lk) ^ swz) << 3)];
            #pragma unroll
            for (int i = 0; i < 4; i++)
                #pragma unroll
                for (int j = 0; j < 2; j++)
                    acc[i][j] = MFMA16(a[i], b[j], acc[i][j]);
        }
    }

    #pragma unroll
    for (int i = 0; i < 4; i++) {
        #pragma unroll
        for (int j = 0; j < 2; j++) {
            #pragma unroll
            for (int r = 0; r < 4; r++) {
                int gm = m0 + wm * 64 + i * 16 + lk * 4 + r;
                int gn = n0 + wn * 32 + j * 16 + lr;
                out[(size_t)gm * 1024 + gn] = acc[i][j][r] + bias[gn];
            }
        }
    }
}

// ---------------------------------------------------------------------------
extern "C" void kernel_launch(void* const* d_in, const int* in_sizes, int n_in,
                              void* d_out, int out_size, void* d_ws, size_t ws_size,
                              hipStream_t stream)
{
    const float* x     = (const float*)d_in[0];
    const float* qkv_w = (const float*)d_in[1];
    const float* qkv_b = (const float*)d_in[2];
    const float* out_w = (const float*)d_in[3];
    const float* out_b = (const float*)d_in[4];
    float* out = (float*)d_out;

    const size_t SZ = (size_t)NB * NH * SEQ * HD;      // 4,194,304
    bf16* Qb  = (bf16*)d_ws;
    bf16* Kb  = Qb + SZ;
    bf16* VbT = Kb + SZ;
    bf16* AO  = VbT + SZ;
    bf16* xb  = AO + SZ;
    bf16* wqb = xb + SZ;
    bf16* wob = wqb + (size_t)3 * D_MODEL * D_MODEL;

    hipLaunchKernelGGL(k_cast_all, dim3(4096), dim3(256), 0, stream,
                       x, qkv_w, out_w, xb, wqb, wob);

    hipLaunchKernelGGL(k_qkv, dim3(32, 24), dim3(256), 0, stream,
                       xb, wqb, qkv_b, Qb, Kb, VbT);
    hipLaunchKernelGGL(k_attn, dim3(32, 32), dim3(256), 0, stream,
                       Qb, Kb, VbT, AO);
    hipLaunchKernelGGL(k_oproj, dim3(32, 16), dim3(256), 0, stream,
                       AO, wob, out_b, out);
}

// Round 13
// 168.572 us; speedup vs baseline: 1.0501x; 1.0210x over previous
//
#include <hip/hip_runtime.h>
#include <hip/hip_bf16.h>

// B=2, T=2048, D=1024, H=16, Hd=64. Inputs/outputs f32; compute bf16 MFMA.

typedef __bf16 bf16;
typedef bf16 bf16x8 __attribute__((ext_vector_type(8)));
typedef bf16 bf16x4 __attribute__((ext_vector_type(4)));
typedef float f32x4 __attribute__((ext_vector_type(4)));

#define MFMA16(a, b, c) __builtin_amdgcn_mfma_f32_16x16x32_bf16((a), (b), (c), 0, 0, 0)

static constexpr int D_MODEL = 1024;
static constexpr int NH = 16;
static constexpr int HD = 64;
static constexpr int SEQ = 2048;
static constexpr int NB = 2;
static constexpr float QSCALE = 0.125f * 1.44269504088896340736f; // 1/sqrt(64)*log2(e)

__device__ __forceinline__ bf16x8 cvt8(const float* p) {
    float4 u0 = *(const float4*)p;
    float4 u1 = *(const float4*)(p + 4);
    bf16x8 v = { (bf16)u0.x, (bf16)u0.y, (bf16)u0.z, (bf16)u0.w,
                 (bf16)u1.x, (bf16)u1.y, (bf16)u1.z, (bf16)u1.w };
    return v;
}

// async global->LDS, 16 B per lane (LDS dest = wave-uniform base + lane*16).
__device__ __forceinline__ void async16(const bf16* g, bf16* l) {
    __builtin_amdgcn_global_load_lds(
        (const __attribute__((address_space(1))) void*)g,
        (__attribute__((address_space(3))) void*)l, 16, 0, 0);
}

// ---------------------------------------------------------------------------
// Kernel 0: merged f32 -> bf16 cast for all three tensors (R16, one launch).
// ---------------------------------------------------------------------------
static constexpr int X8 = 524288;
static constexpr int W8 = 917504;   // X8 + 393216
static constexpr int T8 = 1048576;  // W8 + 131072

__global__ __launch_bounds__(256)
void k_cast_all(const float* __restrict__ x, const float* __restrict__ qkv_w,
                const float* __restrict__ out_w,
                bf16* __restrict__ xb, bf16* __restrict__ wqb,
                bf16* __restrict__ wob)
{
    int i = blockIdx.x * 256 + threadIdx.x;
    if (i < X8) {
        *(bf16x8*)&xb[(size_t)i * 8] = cvt8(&x[(size_t)i * 8]);
    } else if (i < W8) {
        int j = i - X8;
        *(bf16x8*)&wqb[(size_t)j * 8] = cvt8(&qkv_w[(size_t)j * 8]);
    } else if (i < T8) {
        int j = i - W8;
        *(bf16x8*)&wob[(size_t)j * 8] = cvt8(&out_w[(size_t)j * 8]);
    }
}

// ---------------------------------------------------------------------------
// Kernel 1: QKV projection, 128x128 tile, BK=32 — exact R10 version (flat
// LDS, syncthreads, single-buffer). FROZEN: BK=64 regressed (R11: VGPR 88,
// occupancy 14%), 8-phase regressed (R8), counted-vmcnt regressed (R5),
// mod-4 swizzle neutral-negative (R12) -> conflicts are TLP-hidden at 3
// blocks/CU; this kernel is at its staging-latency plateau (~41 µs, 630 TF).
// Q -> [B,H,T,64] (pre-scaled), K -> [B,H,T,64], V -> transposed [B,H,64,T].
// ---------------------------------------------------------------------------
__global__ __launch_bounds__(256)
void k_qkv(const bf16* __restrict__ x, const bf16* __restrict__ w,
           const float* __restrict__ bias,
           bf16* __restrict__ Qb, bf16* __restrict__ Kb, bf16* __restrict__ VbT)
{
    __shared__ bf16 As[128 * 32];   // 8 KB, flat
    __shared__ bf16 Ws[128 * 32];

    const int tid  = threadIdx.x;
    const int wv   = tid >> 6;
    const int lane = tid & 63;
    const int lr   = lane & 15;
    const int lk   = lane >> 4;
    const int wm   = wv >> 1, wn = wv & 1;
    const int m0   = blockIdx.x * 128;
    const int n0   = blockIdx.y * 128;

    const int sRow = tid >> 2;           // 0..63
    const int sCol = (tid & 3) * 8;      // 0,8,16,24
    const int sOff = sRow * 32 + sCol;   // = 16*tid bytes

    f32x4 acc[4][4] = {};

    for (int kt = 0; kt < 1024; kt += 32) {
        __syncthreads();
        async16(&x[(size_t)(m0 + sRow     ) * 1024 + kt + sCol], &As[sOff]);
        async16(&x[(size_t)(m0 + 64 + sRow) * 1024 + kt + sCol], &As[64 * 32 + sOff]);
        async16(&w[(size_t)(n0 + sRow     ) * 1024 + kt + sCol], &Ws[sOff]);
        async16(&w[(size_t)(n0 + 64 + sRow) * 1024 + kt + sCol], &Ws[64 * 32 + sOff]);
        __syncthreads();

        bf16x8 a[4], b[4];
        #pragma unroll
        for (int i = 0; i < 4; i++) {
            a[i] = *(const bf16x8*)&As[(wm * 64 + i * 16 + lr) * 32 + lk * 8];
            b[i] = *(const bf16x8*)&Ws[(wn * 64 + i * 16 + lr) * 32 + lk * 8];
        }
        #pragma unroll
        for (int i = 0; i < 4; i++)
            #pragma unroll
            for (int j = 0; j < 4; j++)
                acc[i][j] = MFMA16(a[i], b[j], acc[i][j]);
    }

    // C/D layout: col = lane&15, row = (lane>>4)*4 + reg
    #pragma unroll
    for (int i = 0; i < 4; i++) {
        #pragma unroll
        for (int j = 0; j < 4; j++) {
            const int gm0 = m0 + wm * 64 + i * 16 + lk * 4;
            const int gn  = n0 + wn * 64 + j * 16 + lr;
            const int sel = gn >> 10;
            const int rem = gn & 1023;
            const int h   = rem >> 6;
            const int hd  = rem & 63;
            const int bb  = gm0 >> 11;
            const int t0  = gm0 & 2047;
            if (sel == 2) {
                bf16x4 p;
                #pragma unroll
                for (int r = 0; r < 4; r++) p[r] = (bf16)(acc[i][j][r] + bias[gn]);
                *(bf16x4*)&VbT[((size_t)(bb * NH + h) * HD + hd) * SEQ + t0] = p;
            } else {
                #pragma unroll
                for (int r = 0; r < 4; r++) {
                    float v = acc[i][j][r] + bias[gn];
                    size_t idx = ((size_t)(bb * NH + h) * SEQ + t0 + r) * HD + hd;
                    if (sel == 0) Qb[idx] = (bf16)(v * QSCALE);
                    else          Kb[idx] = (bf16)v;
                }
            }
        }
    }
}

// ---------------------------------------------------------------------------
// Kernel 2: causal flash attention — R22: exact R1 structure + s_setprio(1)
// around the QK^T and PV MFMA clusters (T5). Mechanism: 4 independent blocks
// per CU sit at different loop phases (serpentine pairing), so MFMA-entering
// waves get pipe priority over other blocks' staging/VALU waves — the m191
// regime (+4-7% attn), NOT m190's lockstep-GEMM null. No layout/sync change.
// QBLK=64, 4 waves x 16 q; double-buffered K/V via global_load_lds one tile
// ahead; counted vmcnt(4) + raw s_barrier; 16B-chunk XOR swizzle with
// pre-swizzled global source; no-max softmax with HW exp; S^T = K·Q^T.
// R2 (fat waves) and R15 (8 thin waves) both regressed — do not re-fatten.
// ---------------------------------------------------------------------------
__global__ __launch_bounds__(256)
void k_attn(const bf16* __restrict__ Qb, const bf16* __restrict__ Kb,
            const bf16* __restrict__ VbT, bf16* __restrict__ AO)
{
    __shared__ bf16 Ks[2][64 * 64];
    __shared__ bf16 Vt[2][64 * 64];
    __shared__ bf16 Ps[64 * 64];

    const int tid  = threadIdx.x;
    const int wv   = tid >> 6;
    const int lane = tid & 63;
    const int lr   = lane & 15;
    const int lk   = lane >> 4;
    const int bh   = blockIdx.y;
    const int qt   = ((bh >> 3) & 1) ? (31 - (int)blockIdx.x) : (int)blockIdx.x;

    const bf16* Qp  = Qb  + (size_t)bh * SEQ * HD;
    const bf16* Kp  = Kb  + (size_t)bh * SEQ * HD;
    const bf16* Vtp = VbT + (size_t)bh * HD * SEQ;

    const int qg = qt * 64 + wv * 16 + lr;

    bf16x8 qf[2];
    qf[0] = *(const bf16x8*)&Qp[(size_t)qg * HD +      lk * 8];
    qf[1] = *(const bf16x8*)&Qp[(size_t)qg * HD + 32 + lk * 8];

    f32x4 ot[4] = {};
    float lsum = 0.f;

    const int srow   = tid >> 3;
    const int sgcol  = ((tid & 7) ^ (srow & 7)) * 8;
    const int sldse  = tid * 8;
    const int swz    = lr & 7;

    auto stage = [&](int buf, int k0) {
        async16(&Kp [(size_t)(k0 + srow     ) * HD  + sgcol], &Ks[buf][       sldse]);
        async16(&Kp [(size_t)(k0 + 32 + srow) * HD  + sgcol], &Ks[buf][2048 + sldse]);
        async16(&Vtp[(size_t)(srow          ) * SEQ + k0 + sgcol], &Vt[buf][       sldse]);
        async16(&Vtp[(size_t)(32 + srow     ) * SEQ + k0 + sgcol], &Vt[buf][2048 + sldse]);
    };

    stage(0, 0);

    for (int kt = 0; kt <= qt; kt++) {
        const int p = kt & 1;
        if (kt < qt) {
            stage(p ^ 1, (kt + 1) * 64);
            asm volatile("s_waitcnt vmcnt(4)" ::: "memory");
        } else {
            asm volatile("s_waitcnt vmcnt(0)" ::: "memory");
        }
        __builtin_amdgcn_s_barrier();

        f32x4 s[4] = {};
        __builtin_amdgcn_s_setprio(1);
        #pragma unroll
        for (int j = 0; j < 4; j++) {
            #pragma unroll
            for (int c = 0; c < 2; c++) {
                bf16x8 ka = *(const bf16x8*)
                    &Ks[p][(j * 16 + lr) * 64 + (((4 * c + lk) ^ swz) << 3)];
                s[j] = MFMA16(ka, qf[c], s[j]);
            }
        }
        __builtin_amdgcn_s_setprio(0);

        const int k0 = kt * 64;
        const bool diag = (kt == qt);
        #pragma unroll
        for (int j = 0; j < 4; j++) {
            const int keyb = k0 + j * 16 + lk * 4;
            f32x4 pv;
            #pragma unroll
            for (int r = 0; r < 4; r++) {
                float e = __builtin_amdgcn_exp2f(s[j][r]);
                if (diag) e = (keyb + r > qg) ? 0.f : e;
                pv[r] = e;
            }
            s[j] = pv;
            lsum += (pv[0] + pv[1]) + (pv[2] + pv[3]);
        }

        #pragma unroll
        for (int j = 0; j < 4; j++) {
            bf16x4 p4 = { (bf16)s[j][0], (bf16)s[j][1], (bf16)s[j][2], (bf16)s[j][3] };
            *(bf16x4*)&Ps[(wv * 16 + lr) * 64 +
                          (((2 * j + (lk >> 1)) ^ swz) << 3) + ((lk & 1) << 2)] = p4;
        }

        __builtin_amdgcn_s_setprio(1);
        #pragma unroll
        for (int c = 0; c < 2; c++) {
            bf16x8 pb = *(const bf16x8*)
                &Ps[(wv * 16 + lr) * 64 + (((4 * c + lk) ^ swz) << 3)];
            #pragma unroll
            for (int jh = 0; jh < 4; jh++) {
                bf16x8 va = *(const bf16x8*)
                    &Vt[p][(jh * 16 + lr) * 64 + (((4 * c + lk) ^ swz) << 3)];
                ot[jh] = MFMA16(va, pb, ot[jh]);
            }
        }
        __builtin_amdgcn_s_setprio(0);

        asm volatile("" ::: "memory");
        __builtin_amdgcn_s_barrier();
    }

    lsum += __shfl_xor(lsum, 16);
    lsum += __shfl_xor(lsum, 32);

    const float inv = 1.0f / lsum;
    const int b_ = bh >> 4, h_ = bh & 15;
    const size_t base = ((size_t)(b_ * SEQ + qg)) * D_MODEL + h_ * HD;
    #pragma unroll
    for (int jh = 0; jh < 4; jh++) {
        bf16x4 o4 = { (bf16)(ot[jh][0] * inv), (bf16)(ot[jh][1] * inv),
                      (bf16)(ot[jh][2] * inv), (bf16)(ot[jh][3] * inv) };
        *(bf16x4*)&AO[base + jh * 16 + lk * 4] = o4;
    }
}

// ---------------------------------------------------------------------------
// Kernel 3: output projection — R19 (measured good: total 171.5 -> 168.9):
// 128x64 tile, BK=64, 16 barriers, swizzled 16B chunks (write source chunk
// (t&7)^(row&7), read ((kk*4+lk)^(lr&7))), piece stride 2048. 24 KB LDS.
// ---------------------------------------------------------------------------
__global__ __launch_bounds__(256)
void k_oproj(const bf16* __restrict__ a_, const bf16* __restrict__ w,
             const float* __restrict__ bias, float* __restrict__ out)
{
    __shared__ bf16 As[128 * 64];   // 16 KB, swizzled 16B chunks
    __shared__ bf16 Ws[64 * 64];    //  8 KB, swizzled

    const int tid  = threadIdx.x;
    const int wv   = tid >> 6;
    const int lane = tid & 63;
    const int lr   = lane & 15;
    const int lk   = lane >> 4;
    const int wm   = wv >> 1, wn = wv & 1;
    const int m0   = blockIdx.x * 128;
    const int n0   = blockIdx.y * 64;

    const int srow   = tid >> 3;                 // 0..31 (row within 32-row piece)
    const int schunk = (tid & 7) ^ (srow & 7);   // swizzled source chunk
    const int sldse  = tid * 8;                  // linear LDS elem within piece
    const int swz    = lr & 7;                   // read-side swizzle key

    f32x4 acc[4][2] = {};

    for (int kt = 0; kt < 1024; kt += 64) {
        __syncthreads();
        #pragma unroll
        for (int l = 0; l < 4; l++)     // A: 4 pieces x 32 rows x 64 k (2048 elems each)
            async16(&a_[(size_t)(m0 + l * 32 + srow) * 1024 + kt + schunk * 8],
                    &As[l * 2048 + sldse]);
        #pragma unroll
        for (int l = 0; l < 2; l++)     // W: 2 pieces x 32 rows x 64 k
            async16(&w [(size_t)(n0 + l * 32 + srow) * 1024 + kt + schunk * 8],
                    &Ws[l * 2048 + sldse]);
        __syncthreads();

        #pragma unroll
        for (int kk = 0; kk < 2; kk++) {
            bf16x8 a[4], b[2];
            #pragma unroll
            for (int i = 0; i < 4; i++)
                a[i] = *(const bf16x8*)
                    &As[(wm * 64 + i * 16 + lr) * 64 + (((kk * 4 + lk) ^ swz) << 3)];
            #pragma unroll
            for (int j = 0; j < 2; j++)
                b[j] = *(const bf16x8*)
                    &Ws[(wn * 32 + j * 16 + lr) * 64 + (((kk * 4 + lk) ^ swz) << 3)];
            #pragma unroll
            for (int i = 0; i < 4; i++)
                #pragma unroll
                for (int j = 0; j < 2; j++)
                    acc[i][j] = MFMA16(a[i], b[j], acc[i][j]);
        }
    }

    #pragma unroll
    for (int i = 0; i < 4; i++) {
        #pragma unroll
        for (int j = 0; j < 2; j++) {
            #pragma unroll
            for (int r = 0; r < 4; r++) {
                int gm = m0 + wm * 64 + i * 16 + lk * 4 + r;
                int gn = n0 + wn * 32 + j * 16 + lr;
                out[(size_t)gm * 1024 + gn] = acc[i][j][r] + bias[gn];
            }
        }
    }
}

// ---------------------------------------------------------------------------
extern "C" void kernel_launch(void* const* d_in, const int* in_sizes, int n_in,
                              void* d_out, int out_size, void* d_ws, size_t ws_size,
                              hipStream_t stream)
{
    const float* x     = (const float*)d_in[0];
    const float* qkv_w = (const float*)d_in[1];
    const float* qkv_b = (const float*)d_in[2];
    const float* out_w = (const float*)d_in[3];
    const float* out_b = (const float*)d_in[4];
    float* out = (float*)d_out;

    const size_t SZ = (size_t)NB * NH * SEQ * HD;      // 4,194,304
    bf16* Qb  = (bf16*)d_ws;
    bf16* Kb  = Qb + SZ;
    bf16* VbT = Kb + SZ;
    bf16* AO  = VbT + SZ;
    bf16* xb  = AO + SZ;
    bf16* wqb = xb + SZ;
    bf16* wob = wqb + (size_t)3 * D_MODEL * D_MODEL;

    hipLaunchKernelGGL(k_cast_all, dim3(4096), dim3(256), 0, stream,
                       x, qkv_w, out_w, xb, wqb, wob);

    hipLaunchKernelGGL(k_qkv, dim3(32, 24), dim3(256), 0, stream,
                       xb, wqb, qkv_b, Qb, Kb, VbT);
    hipLaunchKernelGGL(k_attn, dim3(32, 32), dim3(256), 0, stream,
                       Qb, Kb, VbT, AO);
    hipLaunchKernelGGL(k_oproj, dim3(32, 16), dim3(256), 0, stream,
                       AO, wob, out_b, out);
}